// Round 16
// baseline (254.717 us; speedup 1.0000x reference)
//
#include <hip/hip_runtime.h>
#include <math.h>

// Problem constants
#define B_   128
#define IN_  1024
#define OUT_ 1024
#define E_   32

// moe_main tiling
#define SLAB  64                 // i-rows per block
#define NSLAB (IN_ / SLAB)       // 16
#define S_    16                 // samples per group pass
#define THR   512

// ws layout (bytes)
#define WS_ROUTE   0              // 128*2*4 floats = 4 KB
#define WS_DONE    4096           // 128 ints
#define WS_PART    65536          // 2*NSLAB*B_*OUT_ floats = 16 MB

// ---------------- Kernel A: routing, one block per (sample, router) --------------
// route layout: route[(b*2 + r)*4] = [idx0, idx1, p0, p1]  (idx bit-cast)
// r==1 blocks additionally write out[b] = pb0*eb[ib0] + pb1*eb[ib1] (bias init).
// r==0 blocks zero done[b] (completion counters for the fused reduction).
__global__ __launch_bounds__(256) void route_kernel(
    const float* __restrict__ x, const float* __restrict__ rw,
    const float* __restrict__ brw, const float* __restrict__ eb,
    float* __restrict__ route, float* __restrict__ out, int* __restrict__ done) {
  int b = blockIdx.x;
  int r = blockIdx.y;
  int t = threadIdx.x;
  const float* w = r ? brw : rw;

  __shared__ float xs[IN_];
  __shared__ float part[8][E_];
  __shared__ float lg[E_];
  __shared__ float res[4];

  if (r == 0 && t == 0) done[b] = 0;

  ((float4*)xs)[t] = ((const float4*)(x + (size_t)b * IN_))[t];
  __syncthreads();

  int e  = t & 31;
  int ic = t >> 5;
  int base = ic * 128;
  float acc = 0.f;
  #pragma unroll 8
  for (int i = 0; i < 128; ++i)
    acc += xs[base + i] * w[(size_t)(base + i) * E_ + e];
  part[ic][e] = acc;
  __syncthreads();

  if (t < E_) {
    float s = 0.f;
    #pragma unroll
    for (int q = 0; q < 8; ++q) s += part[q][t];
    lg[t] = s;
  }
  __syncthreads();

  if (t == 0) {
    int bi0 = -1, bi1 = -1;
    float v0 = -INFINITY, v1 = -INFINITY;
    for (int ee = 0; ee < E_; ++ee) {
      float v = lg[ee];
      if (v > v0) { v1 = v0; bi1 = bi0; v0 = v; bi0 = ee; }
      else if (v > v1) { v1 = v; bi1 = ee; }
    }
    float p0 = 1.f / (1.f + expf(v1 - v0));
    float* rp = route + ((size_t)b * 2 + r) * 4;
    rp[0] = __int_as_float(bi0);
    rp[1] = __int_as_float(bi1);
    rp[2] = p0;
    rp[3] = 1.f - p0;
    res[0] = __int_as_float(bi0);
    res[1] = __int_as_float(bi1);
    res[2] = p0;
    res[3] = 1.f - p0;
  }

  if (r == 1) {
    __syncthreads();
    int ib0 = __float_as_int(res[0]);
    int ib1 = __float_as_int(res[1]);
    float pb0 = res[2], pb1 = res[3];
    float4 b0 = ((const float4*)(eb + (size_t)ib0 * OUT_))[t];
    float4 b1 = ((const float4*)(eb + (size_t)ib1 * OUT_))[t];
    float4 o;
    o.x = pb0 * b0.x + pb1 * b1.x;
    o.y = pb0 * b0.y + pb1 * b1.y;
    o.z = pb0 * b0.z + pb1 * b1.z;
    o.w = pb0 * b0.w + pb1 * b1.w;
    ((float4*)(out + (size_t)b * OUT_))[t] = o;
  }
}

// ---------------- Kernel B: probe-shaped expert matvecs + fused reduction --------
// block = (e, slab of 64 i-rows); 512 threads, thread t owns output cols
// [2t, 2t+1]. Per-expert sample list via ballot prefix scan. Inner loop is the
// proven probe shape (8 independent named float2 loads, in-issue-order
// consume). Partials to disjoint ws slots via plain stores (zero atomics on
// the data path). REDUCTION IS FUSED: after stores, threadfence + one
// atomicAdd(done[b]) per handled sample; the block whose add returns 31 (all
// 32 contributions of row b visible) reduces that row with all 512 threads in
// the same scalar order as the old reduce_kernel (bit-identical result).
__global__ __launch_bounds__(THR) void moe_main(
    const float* __restrict__ x, const float* __restrict__ ew,
    const float* __restrict__ route, float* __restrict__ part,
    float* __restrict__ out, int* __restrict__ done) {
  int e    = blockIdx.x;
  int slab = blockIdx.y;

  __shared__ float xs[SLAB][S_];   // [i][s], rows 64B-aligned -> b128 broadcast reads
  __shared__ int   bs[S_];
  __shared__ int   ks[S_];
  __shared__ float ps[S_];
  __shared__ int   ls_b[B_];
  __shared__ int   ls_k[B_];
  __shared__ float ls_p[B_];
  __shared__ int   cnt0_sh, cnt1_sh;
  __shared__ int   rb_list[S_];

  int t  = threadIdx.x;
  int i0 = slab * SLAB;
  const float* wp0 = ew + ((size_t)e * IN_ + i0) * OUT_ + 2 * t;

  // ---- ballot-based per-expert list scan (threads 0..127, waves 0 and 1) ----
  int my_m = 0, my_k = 0, my_rank = 0;
  float my_p = 0.f;
  if (t < B_) {
    float4 r = *(const float4*)(route + (size_t)t * 8);
    bool m0 = (__float_as_int(r.x) == e);
    bool m1 = (!m0) && (__float_as_int(r.y) == e);
    my_m = (m0 || m1) ? 1 : 0;
    my_k = m0 ? 0 : 1;
    my_p = m0 ? r.z : r.w;
    unsigned long long mask = __ballot(my_m != 0);
    int lane = t & 63;
    my_rank = __popcll(mask & ((1ull << lane) - 1ull));
    if (lane == 0) {
      if (t < 64) cnt0_sh = __popcll(mask);
      else        cnt1_sh = __popcll(mask);
    }
  }
  __syncthreads();
  if (my_m) {
    int idx = my_rank + ((t >= 64) ? cnt0_sh : 0);
    ls_b[idx] = t;
    ls_k[idx] = my_k;
    ls_p[idx] = my_p;
  }
  int c = cnt0_sh + cnt1_sh;
  if (c == 0) return;   // uniform: all threads exit together

  for (int g0 = 0; g0 < c; g0 += S_) {
    __syncthreads();   // ls_* ready (first iter) / previous pass's readers done
    if (t < S_) {
      int idx = min(g0 + t, c - 1);
      bs[t] = ls_b[idx];
      ks[t] = ls_k[idx];
      ps[t] = (g0 + t < c) ? ls_p[idx] : 0.f;
    }
    __syncthreads();

    // stage x transposed: thread t -> (s = t&15, row pair 2*(t>>4)), float2
    {
      int s  = t & 15;
      int ip = t >> 4;                    // 0..31
      const float* xr = x + (size_t)bs[s] * IN_ + i0 + 2 * ip;
      float2 v = *(const float2*)xr;
      xs[2 * ip][s]     = v.x;
      xs[2 * ip + 1][s] = v.y;
    }
    __syncthreads();

    float2 acc[S_];
    #pragma unroll
    for (int s = 0; s < S_; ++s) acc[s] = make_float2(0.f, 0.f);

    // probe-shaped stream: batches of 8 rows, loads then in-order consume
    #pragma unroll 1
    for (int ib = 0; ib < SLAB; ib += 8) {
      const float* wp = wp0 + (size_t)ib * OUT_;
      float2 w0 = *(const float2*)(wp);
      float2 w1 = *(const float2*)(wp + (size_t)1 * OUT_);
      float2 w2 = *(const float2*)(wp + (size_t)2 * OUT_);
      float2 w3 = *(const float2*)(wp + (size_t)3 * OUT_);
      float2 w4 = *(const float2*)(wp + (size_t)4 * OUT_);
      float2 w5 = *(const float2*)(wp + (size_t)5 * OUT_);
      float2 w6 = *(const float2*)(wp + (size_t)6 * OUT_);
      float2 w7 = *(const float2*)(wp + (size_t)7 * OUT_);

      #pragma unroll
      for (int r = 0; r < 8; ++r) {
        float2 wv = (r == 0) ? w0 : (r == 1) ? w1 : (r == 2) ? w2 :
                    (r == 3) ? w3 : (r == 4) ? w4 : (r == 5) ? w5 :
                    (r == 6) ? w6 : w7;
        const float4* xr = (const float4*)xs[ib + r];
        float4 xa = xr[0], xb = xr[1], xc = xr[2], xd = xr[3];
        acc[0].x  += xa.x * wv.x;  acc[0].y  += xa.x * wv.y;
        acc[1].x  += xa.y * wv.x;  acc[1].y  += xa.y * wv.y;
        acc[2].x  += xa.z * wv.x;  acc[2].y  += xa.z * wv.y;
        acc[3].x  += xa.w * wv.x;  acc[3].y  += xa.w * wv.y;
        acc[4].x  += xb.x * wv.x;  acc[4].y  += xb.x * wv.y;
        acc[5].x  += xb.y * wv.x;  acc[5].y  += xb.y * wv.y;
        acc[6].x  += xb.z * wv.x;  acc[6].y  += xb.z * wv.y;
        acc[7].x  += xb.w * wv.x;  acc[7].y  += xb.w * wv.y;
        acc[8].x  += xc.x * wv.x;  acc[8].y  += xc.x * wv.y;
        acc[9].x  += xc.y * wv.x;  acc[9].y  += xc.y * wv.y;
        acc[10].x += xc.z * wv.x;  acc[10].y += xc.z * wv.y;
        acc[11].x += xc.w * wv.x;  acc[11].y += xc.w * wv.y;
        acc[12].x += xd.x * wv.x;  acc[12].y += xd.x * wv.y;
        acc[13].x += xd.y * wv.x;  acc[13].y += xd.y * wv.y;
        acc[14].x += xd.z * wv.x;  acc[14].y += xd.z * wv.y;
        acc[15].x += xd.w * wv.x;  acc[15].y += xd.w * wv.y;
      }
    }

    // epilogue: plain store into the disjoint partial slot (p applied here)
    #pragma unroll
    for (int s = 0; s < S_; ++s) {
      if (g0 + s < c) {
        float p = ps[s];
        float* op = part + (((size_t)ks[s] * NSLAB + slab) * B_ + bs[s]) * OUT_ + 2 * t;
        op[0] = p * acc[s].x;
        op[1] = p * acc[s].y;
      }
    }

    // ---- fused reduction: last contributor of row b reduces it ----
    __threadfence();           // make this thread's partial stores device-visible
    __syncthreads();           // all threads' stores fenced before counting
    if (t < S_) {
      int flag = -1;
      if (g0 + t < c) {
        int old = atomicAdd(&done[bs[t]], 1);
        if (old == 31) flag = bs[t];   // all 32 contributions in, all fenced
      }
      rb_list[t] = flag;
    }
    __syncthreads();
    __threadfence();           // acquire: invalidate L1 before reading remote partials
    for (int j = 0; j < S_; ++j) {
      int rb = rb_list[j];
      if (rb < 0) continue;
      float2 a = *(const float2*)(out + (size_t)rb * OUT_ + 2 * t);   // bias
      #pragma unroll
      for (int k = 0; k < 2; ++k) {
        #pragma unroll
        for (int sl = 0; sl < NSLAB; ++sl) {
          float2 v = *(const float2*)(part + (((size_t)k * NSLAB + sl) * B_ + rb) * OUT_ + 2 * t);
          a.x += v.x; a.y += v.y;
        }
      }
      *(float2*)(out + (size_t)rb * OUT_ + 2 * t) = a;
    }
  }
}

extern "C" void kernel_launch(void* const* d_in, const int* in_sizes, int n_in,
                              void* d_out, int out_size, void* d_ws, size_t ws_size,
                              hipStream_t stream) {
  const float* x   = (const float*)d_in[0];
  const float* rw  = (const float*)d_in[1];
  const float* brw = (const float*)d_in[2];
  const float* ew  = (const float*)d_in[3];
  const float* eb  = (const float*)d_in[4];
  float* out = (float*)d_out;

  char* ws = (char*)d_ws;
  float* route = (float*)(ws + WS_ROUTE);
  int*   done  = (int*)(ws + WS_DONE);
  float* part  = (float*)(ws + WS_PART);   // 2*NSLAB*B_*OUT_ floats = 16 MB

  route_kernel<<<dim3(B_, 2), 256, 0, stream>>>(x, rw, brw, eb, route, out, done);
  moe_main<<<dim3(E_, NSLAB), THR, 0, stream>>>(x, ew, route, part, out, done);
}

// Round 17
// 42.143 us; speedup vs baseline: 6.0441x; 6.0441x over previous
//
#include <hip/hip_runtime.h>
#include <math.h>

// Problem constants
#define B_   128
#define IN_  1024
#define OUT_ 1024
#define E_   32

// moe_main tiling
#define SLAB  64                 // i-rows per block
#define NSLAB (IN_ / SLAB)       // 16
#define S_    16                 // samples per group pass
#define THR   512

// ws layout (bytes)
#define WS_ROUTE   0
#define WS_PART    65536          // 2*NSLAB*B_*OUT_ floats = 16 MB

// ---------------- Kernel A: routing, one block per (sample, router) --------------
// route layout: route[(b*2 + r)*4] = [idx0, idx1, p0, p1]  (idx bit-cast)
// r==1 blocks additionally write out[b] = pb0*eb[ib0] + pb1*eb[ib1] (bias init).
__global__ __launch_bounds__(256) void route_kernel(
    const float* __restrict__ x, const float* __restrict__ rw,
    const float* __restrict__ brw, const float* __restrict__ eb,
    float* __restrict__ route, float* __restrict__ out) {
  int b = blockIdx.x;
  int r = blockIdx.y;
  int t = threadIdx.x;
  const float* w = r ? brw : rw;

  __shared__ float xs[IN_];
  __shared__ float part[8][E_];
  __shared__ float lg[E_];
  __shared__ float res[4];

  ((float4*)xs)[t] = ((const float4*)(x + (size_t)b * IN_))[t];
  __syncthreads();

  int e  = t & 31;
  int ic = t >> 5;
  int base = ic * 128;
  float acc = 0.f;
  #pragma unroll 8
  for (int i = 0; i < 128; ++i)
    acc += xs[base + i] * w[(size_t)(base + i) * E_ + e];
  part[ic][e] = acc;
  __syncthreads();

  if (t < E_) {
    float s = 0.f;
    #pragma unroll
    for (int q = 0; q < 8; ++q) s += part[q][t];
    lg[t] = s;
  }
  __syncthreads();

  if (t == 0) {
    int bi0 = -1, bi1 = -1;
    float v0 = -INFINITY, v1 = -INFINITY;
    for (int ee = 0; ee < E_; ++ee) {
      float v = lg[ee];
      if (v > v0) { v1 = v0; bi1 = bi0; v0 = v; bi0 = ee; }
      else if (v > v1) { v1 = v; bi1 = ee; }
    }
    float p0 = 1.f / (1.f + expf(v1 - v0));
    float* rp = route + ((size_t)b * 2 + r) * 4;
    rp[0] = __int_as_float(bi0);
    rp[1] = __int_as_float(bi1);
    rp[2] = p0;
    rp[3] = 1.f - p0;
    res[0] = __int_as_float(bi0);
    res[1] = __int_as_float(bi1);
    res[2] = p0;
    res[3] = 1.f - p0;
  }

  if (r == 1) {
    __syncthreads();
    int ib0 = __float_as_int(res[0]);
    int ib1 = __float_as_int(res[1]);
    float pb0 = res[2], pb1 = res[3];
    float4 b0 = ((const float4*)(eb + (size_t)ib0 * OUT_))[t];
    float4 b1 = ((const float4*)(eb + (size_t)ib1 * OUT_))[t];
    float4 o;
    o.x = pb0 * b0.x + pb1 * b1.x;
    o.y = pb0 * b0.y + pb1 * b1.y;
    o.z = pb0 * b0.z + pb1 * b1.z;
    o.w = pb0 * b0.w + pb1 * b1.w;
    ((float4*)(out + (size_t)b * OUT_))[t] = o;
  }
}

// ---------------- Kernel B: probe-shaped expert matvecs, fused list scan ---------
// block = (e, slab of 64 i-rows); 512 threads, thread t owns output cols
// [2t, 2t+1]. Per-expert sample list built IN-BLOCK via ballot prefix scan.
// Inner loop is probe_strided's proven shape (3.6 TB/s HBM): 8 independent
// named float2 loads issued back-to-back, consumed IN ISSUE ORDER (descending
// vmcnt waits keep 7 loads in flight). No register rotation. Partials to
// disjoint ws slots via plain stores (zero atomics).
__global__ __launch_bounds__(THR) void moe_main(
    const float* __restrict__ x, const float* __restrict__ ew,
    const float* __restrict__ route, float* __restrict__ part) {
  int e    = blockIdx.x;
  int slab = blockIdx.y;

  __shared__ float xs[SLAB][S_];   // [i][s], rows 64B-aligned -> b128 broadcast reads
  __shared__ int   bs[S_];
  __shared__ int   ks[S_];
  __shared__ float ps[S_];
  __shared__ int   ls_b[B_];
  __shared__ int   ls_k[B_];
  __shared__ float ls_p[B_];
  __shared__ int   cnt0_sh, cnt1_sh;

  int t  = threadIdx.x;
  int i0 = slab * SLAB;
  const float* wp0 = ew + ((size_t)e * IN_ + i0) * OUT_ + 2 * t;

  // ---- ballot-based per-expert list scan (threads 0..127, waves 0 and 1) ----
  int my_m = 0, my_k = 0, my_rank = 0;
  float my_p = 0.f;
  if (t < B_) {
    float4 r = *(const float4*)(route + (size_t)t * 8);
    bool m0 = (__float_as_int(r.x) == e);
    bool m1 = (!m0) && (__float_as_int(r.y) == e);
    my_m = (m0 || m1) ? 1 : 0;
    my_k = m0 ? 0 : 1;
    my_p = m0 ? r.z : r.w;
    unsigned long long mask = __ballot(my_m != 0);
    int lane = t & 63;
    my_rank = __popcll(mask & ((1ull << lane) - 1ull));
    if (lane == 0) {
      if (t < 64) cnt0_sh = __popcll(mask);
      else        cnt1_sh = __popcll(mask);
    }
  }
  __syncthreads();
  if (my_m) {
    int idx = my_rank + ((t >= 64) ? cnt0_sh : 0);
    ls_b[idx] = t;
    ls_k[idx] = my_k;
    ls_p[idx] = my_p;
  }
  int c = cnt0_sh + cnt1_sh;
  if (c == 0) return;   // uniform: all threads exit together

  for (int g0 = 0; g0 < c; g0 += S_) {
    __syncthreads();   // ls_* ready (first iter) / previous pass's readers done
    if (t < S_) {
      int idx = min(g0 + t, c - 1);
      bs[t] = ls_b[idx];
      ks[t] = ls_k[idx];
      ps[t] = (g0 + t < c) ? ls_p[idx] : 0.f;
    }
    __syncthreads();

    // stage x transposed: thread t -> (s = t&15, row pair 2*(t>>4)), float2
    {
      int s  = t & 15;
      int ip = t >> 4;                    // 0..31
      const float* xr = x + (size_t)bs[s] * IN_ + i0 + 2 * ip;
      float2 v = *(const float2*)xr;
      xs[2 * ip][s]     = v.x;
      xs[2 * ip + 1][s] = v.y;
    }
    __syncthreads();

    float2 acc[S_];
    #pragma unroll
    for (int s = 0; s < S_; ++s) acc[s] = make_float2(0.f, 0.f);

    // probe-shaped stream: batches of 8 rows, loads then in-order consume
    #pragma unroll 1
    for (int ib = 0; ib < SLAB; ib += 8) {
      const float* wp = wp0 + (size_t)ib * OUT_;
      float2 w0 = *(const float2*)(wp);
      float2 w1 = *(const float2*)(wp + (size_t)1 * OUT_);
      float2 w2 = *(const float2*)(wp + (size_t)2 * OUT_);
      float2 w3 = *(const float2*)(wp + (size_t)3 * OUT_);
      float2 w4 = *(const float2*)(wp + (size_t)4 * OUT_);
      float2 w5 = *(const float2*)(wp + (size_t)5 * OUT_);
      float2 w6 = *(const float2*)(wp + (size_t)6 * OUT_);
      float2 w7 = *(const float2*)(wp + (size_t)7 * OUT_);

      #pragma unroll
      for (int r = 0; r < 8; ++r) {
        float2 wv = (r == 0) ? w0 : (r == 1) ? w1 : (r == 2) ? w2 :
                    (r == 3) ? w3 : (r == 4) ? w4 : (r == 5) ? w5 :
                    (r == 6) ? w6 : w7;
        const float4* xr = (const float4*)xs[ib + r];
        float4 xa = xr[0], xb = xr[1], xc = xr[2], xd = xr[3];
        acc[0].x  += xa.x * wv.x;  acc[0].y  += xa.x * wv.y;
        acc[1].x  += xa.y * wv.x;  acc[1].y  += xa.y * wv.y;
        acc[2].x  += xa.z * wv.x;  acc[2].y  += xa.z * wv.y;
        acc[3].x  += xa.w * wv.x;  acc[3].y  += xa.w * wv.y;
        acc[4].x  += xb.x * wv.x;  acc[4].y  += xb.x * wv.y;
        acc[5].x  += xb.y * wv.x;  acc[5].y  += xb.y * wv.y;
        acc[6].x  += xb.z * wv.x;  acc[6].y  += xb.z * wv.y;
        acc[7].x  += xb.w * wv.x;  acc[7].y  += xb.w * wv.y;
        acc[8].x  += xc.x * wv.x;  acc[8].y  += xc.x * wv.y;
        acc[9].x  += xc.y * wv.x;  acc[9].y  += xc.y * wv.y;
        acc[10].x += xc.z * wv.x;  acc[10].y += xc.z * wv.y;
        acc[11].x += xc.w * wv.x;  acc[11].y += xc.w * wv.y;
        acc[12].x += xd.x * wv.x;  acc[12].y += xd.x * wv.y;
        acc[13].x += xd.y * wv.x;  acc[13].y += xd.y * wv.y;
        acc[14].x += xd.z * wv.x;  acc[14].y += xd.z * wv.y;
        acc[15].x += xd.w * wv.x;  acc[15].y += xd.w * wv.y;
      }
    }

    // epilogue: plain store into the disjoint partial slot (p applied here)
    #pragma unroll
    for (int s = 0; s < S_; ++s) {
      if (g0 + s < c) {
        float p = ps[s];
        float* op = part + (((size_t)ks[s] * NSLAB + slab) * B_ + bs[s]) * OUT_ + 2 * t;
        op[0] = p * acc[s].x;
        op[1] = p * acc[s].y;
      }
    }
  }
}

// ---------------- Kernel C: reduce partials into out (2-way split rows) ----------
// grid (B_, 2), 128 threads: block (b, h) reduces cols [h*512, h*512+512).
// Same per-element scalar order as before (bit-identical).
__global__ __launch_bounds__(128) void reduce_kernel(
    const float* __restrict__ part, float* __restrict__ out) {
  int b = blockIdx.x;
  int h = blockIdx.y;
  int t = threadIdx.x;                      // 128
  int c4 = h * 128 + t;                     // float4 index within the row
  float4 a = ((const float4*)(out + (size_t)b * OUT_))[c4];
  #pragma unroll
  for (int k = 0; k < 2; ++k) {
    #pragma unroll
    for (int sl = 0; sl < NSLAB; ++sl) {
      float4 v = ((const float4*)(part + (((size_t)k * NSLAB + sl) * B_ + b) * OUT_))[c4];
      a.x += v.x; a.y += v.y; a.z += v.z; a.w += v.w;
    }
  }
  ((float4*)(out + (size_t)b * OUT_))[c4] = a;
}

extern "C" void kernel_launch(void* const* d_in, const int* in_sizes, int n_in,
                              void* d_out, int out_size, void* d_ws, size_t ws_size,
                              hipStream_t stream) {
  const float* x   = (const float*)d_in[0];
  const float* rw  = (const float*)d_in[1];
  const float* brw = (const float*)d_in[2];
  const float* ew  = (const float*)d_in[3];
  const float* eb  = (const float*)d_in[4];
  float* out = (float*)d_out;

  char* ws = (char*)d_ws;
  float* route = (float*)(ws + WS_ROUTE);
  float* part  = (float*)(ws + WS_PART);   // 2*NSLAB*B_*OUT_ floats = 16 MB

  route_kernel<<<dim3(B_, 2), 256, 0, stream>>>(x, rw, brw, eb, route, out);
  moe_main<<<dim3(E_, NSLAB), THR, 0, stream>>>(x, ew, route, part);
  reduce_kernel<<<dim3(B_, 2), 128, 0, stream>>>(part, out);
}